// Round 4
// baseline (1902.561 us; speedup 1.0000x reference)
//
#include <hip/hip_runtime.h>
#include <cstdint>
#include <cstddef>

typedef _Float16 half8 __attribute__((ext_vector_type(8)));
typedef _Float16 half4 __attribute__((ext_vector_type(4)));
typedef float floatx4 __attribute__((ext_vector_type(4)));

#define BATCH 256
#define NCHK 512
#define NVAR 1024
#define EDGE 3072

// ---- check MLP tiling ----
#define NT1C  26     // hidden 388 -> 416 -> 26 col-tiles
#define SC_C  13     // 13 chunks of 32 hidden
#define NT2C  6      // out 96 -> 6 tiles
// ---- var MLP tiling ----
#define NT1V  13     // hidden 196 -> 208 -> 13 col-tiles
#define SC_V  7      // GEMM2 K padded 224 -> 7 chunks of 32
#define NT2V  4      // out 49 -> 64 -> 4 tiles

#define HSTR 40      // LDS H-scratch row stride in halves (80 B: 16B-aligned, 2-way banks)
#define WAVES 16

__device__ __forceinline__ float gelu_f(float x) {
  // exact gelu via A&S 7.1.26 erf approx, |err(erf)| < 1.5e-7
  float ax = fabsf(x) * 0.70710678118654752440f;
  float t  = 1.0f / (1.0f + 0.3275911f * ax);
  float p  = t * (0.254829592f + t * (-0.284496736f + t * (1.421413741f +
             t * (-1.453152027f + t * 1.061405429f))));
  float e  = __expf(-ax * ax);
  float erfv = 1.0f - p * e;
  float s  = (x >= 0.0f) ? erfv : -erfv;
  return 0.5f * x * (1.0f + s);
}

// Pack weights fp32->fp16 into MFMA fragment-major layout:
// frag[(s*NT + nt)*64 + lane][j] = W[k = s*32 + (lane>>4)*8 + j][n = nt*16 + (lane&15)]
// Also builds ipm = argsort(perm): ipm[perm[k]] = k.
__global__ void pack_kernel(const float* __restrict__ cW1, const float* __restrict__ cb1,
                            const float* __restrict__ cW2, const float* __restrict__ cb2,
                            const float* __restrict__ vW1, const float* __restrict__ vb1,
                            const float* __restrict__ vW2, const float* __restrict__ vb2,
                            const int* __restrict__ perm,
                            _Float16* __restrict__ w1c, _Float16* __restrict__ w2c,
                            _Float16* __restrict__ w1v, _Float16* __restrict__ w2v,
                            float* __restrict__ b1c, float* __restrict__ w96c,
                            float* __restrict__ b2c, float* __restrict__ b1v,
                            float* __restrict__ b2v, int* __restrict__ ipm)
{
  int id = blockIdx.x * 256 + threadIdx.x;
  const int S0 = 3 * NT1C * 64;      // 4992
  const int S1 = SC_C * NT2C * 64;   // 4992
  const int S2 = 2 * NT1V * 64;      // 1664
  const int S3 = SC_V * NT2V * 64;   // 1792
  if (id < S0) {
    int s = id / (NT1C * 64), rem = id % (NT1C * 64), nt = rem / 64, l = rem % 64;
    int q = l >> 4, n = nt * 16 + (l & 15);
    half8 v;
    #pragma unroll
    for (int j = 0; j < 8; ++j) {
      int k = s * 32 + q * 8 + j;
      float x = (n < 388) ? cW1[k * 388 + n] : 0.0f;
      v[j] = (_Float16)x;
    }
    *(half8*)(w1c + (size_t)id * 8) = v;
    return;
  }
  id -= S0;
  if (id < S1) {
    int s = id / (NT2C * 64), rem = id % (NT2C * 64), nt = rem / 64, l = rem % 64;
    int q = l >> 4, n = nt * 16 + (l & 15);
    half8 v;
    #pragma unroll
    for (int j = 0; j < 8; ++j) {
      int k = s * 32 + q * 8 + j;
      float x = (k < 388) ? cW2[k * 96 + n] : 0.0f;
      v[j] = (_Float16)x;
    }
    *(half8*)(w2c + (size_t)id * 8) = v;
    return;
  }
  id -= S1;
  if (id < S2) {
    int s = id / (NT1V * 64), rem = id % (NT1V * 64), nt = rem / 64, l = rem % 64;
    int q = l >> 4, n = nt * 16 + (l & 15);
    half8 v;
    #pragma unroll
    for (int j = 0; j < 8; ++j) {
      int k = s * 32 + q * 8 + j;                        // row 48 = prior row
      float x = (k < 49 && n < 196) ? vW1[k * 196 + n] : 0.0f;
      v[j] = (_Float16)x;
    }
    *(half8*)(w1v + (size_t)id * 8) = v;
    return;
  }
  id -= S2;
  if (id < S3) {
    int s = id / (NT2V * 64), rem = id % (NT2V * 64), nt = rem / 64, l = rem % 64;
    int q = l >> 4, n = nt * 16 + (l & 15);
    half8 v;
    #pragma unroll
    for (int j = 0; j < 8; ++j) {
      int k = s * 32 + q * 8 + j;
      float x = (k < 196 && n < 49) ? vW2[k * 49 + n] : 0.0f;
      v[j] = (_Float16)x;
    }
    *(half8*)(w2v + (size_t)id * 8) = v;
    return;
  }
  id -= S3;
  if (id < 416) { b1c[id]  = (id < 388) ? cb1[id] : 0.0f; return; }
  id -= 416;
  if (id < 416) { w96c[id] = (id < 388) ? cW1[96 * 388 + id] : 0.0f; return; }
  id -= 416;
  if (id < 96)  { b2c[id]  = cb2[id]; return; }
  id -= 96;
  if (id < 208) { b1v[id]  = (id < 196) ? vb1[id] : 0.0f; return; }
  id -= 208;
  if (id < 64)  { b2v[id]  = (id < 49) ? vb2[id] : 0.0f; return; }
  id -= 64;
  if (id < EDGE) { ipm[perm[id]] = id; return; }
}

// Fully fused decoder: one block per batch row, message state M resident in LDS
// (var-order edge rows of 16 halves). All T iterations run locally.
// Check phase: gather A-frags via ipm (LDS b128), MLP, scatter via ipm (LDS b64).
// Var phase: contiguous LDS reads/writes, llr -> global.
// Edge ownership is exclusive per check and per var -> only 2 barriers/iter.
__global__ __launch_bounds__(1024, 4) void fused_kernel(
    const int* __restrict__ synd, const float* __restrict__ prior,
    const int* __restrict__ ipm, float* __restrict__ outp,
    const _Float16* __restrict__ W1c, const _Float16* __restrict__ W2c,
    const float* __restrict__ b1c, const float* __restrict__ w96c,
    const float* __restrict__ b2c,
    const _Float16* __restrict__ W1v, const _Float16* __restrict__ W2v,
    const float* __restrict__ b1v, const float* __restrict__ b2v, int T)
{
  __shared__ _Float16 M[EDGE * 16];          // 96 KiB message state
  __shared__ _Float16 HL[WAVES][32 * HSTR];  // 40 KiB per-wave H scratch

  const int tid = threadIdx.x, w = tid >> 6, l = tid & 63;
  const int q = l >> 4, c = l & 15;
  const int b = blockIdx.x;

  // ---- init M: M[3v+j][0] = prior[v], rest 0 (var order) ----
  {
    const int v = tid;                 // 1024 threads, one var each
    float pv = prior[v];
    half8 z = {0,0,0,0,0,0,0,0};
    half8 z0 = z; z0[0] = (_Float16)pv;
    _Float16* dst = M + v * 48;
    *(half8*)(dst)      = z0;  *(half8*)(dst + 8)  = z;
    *(half8*)(dst + 16) = z0;  *(half8*)(dst + 24) = z;
    *(half8*)(dst + 32) = z0;  *(half8*)(dst + 40) = z;
  }

  // ---- per-lane loop-invariant constants ----
  const int chk0 = w * 32;
  float sg[2];
  int ip_e[2][6];
  #pragma unroll
  for (int rg = 0; rg < 2; ++rg) {
    const int chk = chk0 + rg * 16 + c;
    sg[rg] = 1.0f - 2.0f * (float)synd[b * NCHK + chk];
    #pragma unroll
    for (int j = 0; j < 6; ++j) ip_e[rg][j] = ipm[chk * 6 + j];
  }
  const int hi = (l >> 5) & 1;         // q>>1
  float pr[2][2];
  #pragma unroll
  for (int vt = 0; vt < 2; ++vt)
    #pragma unroll
    for (int rg = 0; rg < 2; ++rg)
      pr[vt][rg] = prior[w * 64 + vt * 32 + rg * 16 + c];

  const half8* W1fc = (const half8*)W1c;
  const half8* W2fc = (const half8*)W2c;
  const half8* W1fv = (const half8*)W1v;
  const half8* W2fv = (const half8*)W2v;
  _Float16* Hb = &HL[w][0];

  __syncthreads();

  for (int t = 0; t < T; ++t) {
    // ================= CHECK PHASE (512 rows, 32/wave) =================
    half8 mb[2][3];
    #pragma unroll
    for (int rg = 0; rg < 2; ++rg)
      #pragma unroll
      for (int ks = 0; ks < 3; ++ks) {
        const int ip = hi ? ip_e[rg][2 * ks + 1] : ip_e[rg][2 * ks];
        mb[rg][ks] = *(const half8*)(M + ip * 16 + (q & 1) * 8);
      }

    floatx4 acc2[2][6];
    #pragma unroll
    for (int nt = 0; nt < 6; ++nt) {
      floatx4 bia = *(const floatx4*)(b2c + nt * 16 + q * 4);
      acc2[0][nt] = bia;
      acc2[1][nt] = bia;
    }

    #pragma unroll 2
    for (int s = 0; s < SC_C; ++s) {
      #pragma unroll
      for (int u = 0; u < 2; ++u) {
        const int nt = s * 2 + u;
        half8 wa0 = W1fc[(0 * NT1C + nt) * 64 + l];
        half8 wa1 = W1fc[(1 * NT1C + nt) * 64 + l];
        half8 wa2 = W1fc[(2 * NT1C + nt) * 64 + l];
        floatx4 bia = *(const floatx4*)(b1c  + nt * 16 + q * 4);
        floatx4 wsg = *(const floatx4*)(w96c + nt * 16 + q * 4);
        #pragma unroll
        for (int rg = 0; rg < 2; ++rg) {
          floatx4 a;
          #pragma unroll
          for (int r = 0; r < 4; ++r) a[r] = bia[r] + sg[rg] * wsg[r];
          a = __builtin_amdgcn_mfma_f32_16x16x32_f16(wa0, mb[rg][0], a, 0, 0, 0);
          a = __builtin_amdgcn_mfma_f32_16x16x32_f16(wa1, mb[rg][1], a, 0, 0, 0);
          a = __builtin_amdgcn_mfma_f32_16x16x32_f16(wa2, mb[rg][2], a, 0, 0, 0);
          half4 hh;
          #pragma unroll
          for (int r = 0; r < 4; ++r)
            hh[r] = (_Float16)gelu_f(a[r]);
          *(half4*)(Hb + (rg * 16 + c) * HSTR + u * 16 + q * 4) = hh;
        }
      }
      half8 hf0 = *(const half8*)(Hb + (c)      * HSTR + q * 8);
      half8 hf1 = *(const half8*)(Hb + (16 + c) * HSTR + q * 8);
      #pragma unroll
      for (int nt = 0; nt < 6; ++nt) {
        half8 wb = W2fc[(s * NT2C + nt) * 64 + l];
        acc2[0][nt] = __builtin_amdgcn_mfma_f32_16x16x32_f16(wb, hf0, acc2[0][nt], 0, 0, 0);
        acc2[1][nt] = __builtin_amdgcn_mfma_f32_16x16x32_f16(wb, hf1, acc2[1][nt], 0, 0, 0);
      }
    }

    // scatter outputs back to M via ipm (LDS, 8B granules — no HBM amplification)
    #pragma unroll
    for (int rg = 0; rg < 2; ++rg)
      #pragma unroll
      for (int nt = 0; nt < 6; ++nt) {
        half4 yy;
        #pragma unroll
        for (int r = 0; r < 4; ++r)
          yy[r] = (_Float16)(acc2[rg][nt][r] * sg[rg]);
        *(half4*)(M + ip_e[rg][nt] * 16 + q * 4) = yy;
      }

    __syncthreads();

    // ================= VAR PHASE (1024 rows, 64/wave in 2 sub-passes) =========
    #pragma unroll
    for (int vt = 0; vt < 2; ++vt) {
      const int vbase = w * 64 + vt * 32;
      half8 vb[2][2];
      #pragma unroll
      for (int rg = 0; rg < 2; ++rg) {
        const int v = vbase + rg * 16 + c;
        const _Float16* Xr = M + v * 48;
        vb[rg][0] = *(const half8*)(Xr + q * 8);
        half8 m1 = {0,0,0,0,0,0,0,0};
        if (q < 2) m1 = *(const half8*)(Xr + 32 + q * 8);
        else if (q == 2) m1[0] = (_Float16)pr[vt][rg];
        vb[rg][1] = m1;
      }

      floatx4 accv[2][4];
      #pragma unroll
      for (int nt = 0; nt < 4; ++nt) {
        floatx4 bia = *(const floatx4*)(b2v + nt * 16 + q * 4);
        accv[0][nt] = bia;
        accv[1][nt] = bia;
      }

      #pragma unroll 2
      for (int s = 0; s < SC_V; ++s) {
        #pragma unroll
        for (int u = 0; u < 2; ++u) {
          const int nt = s * 2 + u;
          if (nt < NT1V) {
            half8 wa0 = W1fv[(0 * NT1V + nt) * 64 + l];
            half8 wa1 = W1fv[(1 * NT1V + nt) * 64 + l];
            floatx4 bia = *(const floatx4*)(b1v + nt * 16 + q * 4);
            #pragma unroll
            for (int rg = 0; rg < 2; ++rg) {
              floatx4 a = bia;
              a = __builtin_amdgcn_mfma_f32_16x16x32_f16(wa0, vb[rg][0], a, 0, 0, 0);
              a = __builtin_amdgcn_mfma_f32_16x16x32_f16(wa1, vb[rg][1], a, 0, 0, 0);
              half4 hh;
              #pragma unroll
              for (int r = 0; r < 4; ++r)
                hh[r] = (_Float16)gelu_f(a[r]);
              *(half4*)(Hb + (rg * 16 + c) * HSTR + u * 16 + q * 4) = hh;
            }
          } else {
            half4 hz = {0,0,0,0};
            #pragma unroll
            for (int rg = 0; rg < 2; ++rg)
              *(half4*)(Hb + (rg * 16 + c) * HSTR + u * 16 + q * 4) = hz;
          }
        }
        half8 hf0 = *(const half8*)(Hb + (c)      * HSTR + q * 8);
        half8 hf1 = *(const half8*)(Hb + (16 + c) * HSTR + q * 8);
        #pragma unroll
        for (int nt = 0; nt < 4; ++nt) {
          half8 wb = W2fv[(s * NT2V + nt) * 64 + l];
          accv[0][nt] = __builtin_amdgcn_mfma_f32_16x16x32_f16(wb, hf0, accv[0][nt], 0, 0, 0);
          accv[1][nt] = __builtin_amdgcn_mfma_f32_16x16x32_f16(wb, hf1, accv[1][nt], 0, 0, 0);
        }
      }

      // write back new messages (contiguous, var order) + llr to global
      #pragma unroll
      for (int rg = 0; rg < 2; ++rg) {
        const int v = vbase + rg * 16 + c;
        #pragma unroll
        for (int nt = 0; nt < 3; ++nt) {
          half4 yy;
          #pragma unroll
          for (int r = 0; r < 4; ++r)
            yy[r] = (_Float16)accv[rg][nt][r];
          *(half4*)(M + v * 48 + nt * 16 + q * 4) = yy;
        }
        if (q == 0)
          outp[(size_t)t * (BATCH * NVAR) + b * NVAR + v] = accv[rg][3][0];
      }
    }

    __syncthreads();
  }
}

extern "C" void kernel_launch(void* const* d_in, const int* in_sizes, int n_in,
                              void* d_out, int out_size, void* d_ws, size_t ws_size,
                              hipStream_t stream)
{
  const int*   synd  = (const int*)d_in[0];
  const float* prior = (const float*)d_in[2];
  const int*   perm  = (const int*)d_in[3];
  const float* cW1 = (const float*)d_in[4];
  const float* cb1 = (const float*)d_in[5];
  const float* cW2 = (const float*)d_in[6];
  const float* cb2 = (const float*)d_in[7];
  const float* vW1 = (const float*)d_in[8];
  const float* vb1 = (const float*)d_in[9];
  const float* vW2 = (const float*)d_in[10];
  const float* vb2 = (const float*)d_in[11];
  float* outp = (float*)d_out;
  const int T = out_size / (BATCH * NVAR);

  char* p = (char*)d_ws;
  _Float16* w1c = (_Float16*)p; p += (size_t)3 * NT1C * 64 * 8 * 2;
  _Float16* w2c = (_Float16*)p; p += (size_t)SC_C * NT2C * 64 * 8 * 2;
  _Float16* w1v = (_Float16*)p; p += (size_t)2 * NT1V * 64 * 8 * 2;
  _Float16* w2v = (_Float16*)p; p += (size_t)SC_V * NT2V * 64 * 8 * 2;
  float* b1c  = (float*)p; p += 416 * 4;
  float* w96c = (float*)p; p += 416 * 4;
  float* b2c  = (float*)p; p += 96 * 4;
  float* b1v  = (float*)p; p += 208 * 4;
  float* b2v  = (float*)p; p += 64 * 4;
  int*   ipm  = (int*)p;   p += EDGE * 4;

  pack_kernel<<<(17712 + 255) / 256, 256, 0, stream>>>(
      cW1, cb1, cW2, cb2, vW1, vb1, vW2, vb2, perm,
      w1c, w2c, w1v, w2v, b1c, w96c, b2c, b1v, b2v, ipm);

  fused_kernel<<<BATCH, 1024, 0, stream>>>(
      synd, prior, ipm, outp,
      w1c, w2c, b1c, w96c, b2c, w1v, w2v, b1v, b2v, T);
}

// Round 5
// 1761.463 us; speedup vs baseline: 1.0801x; 1.0801x over previous
//
#include <hip/hip_runtime.h>
#include <cstdint>
#include <cstddef>

typedef _Float16 half8 __attribute__((ext_vector_type(8)));
typedef _Float16 half4 __attribute__((ext_vector_type(4)));
typedef float floatx4 __attribute__((ext_vector_type(4)));

#define BATCH 256
#define NCHK 512
#define NVAR 1024
#define EDGE 3072

// ---- check MLP tiling ----
#define NT1C  26     // hidden 388 -> 416 -> 26 col-tiles
#define SC_C  13     // 13 chunks of 32 hidden
#define NT2C  6      // out 96 -> 6 tiles
// ---- var MLP tiling ----
#define NT1V  13     // hidden 196 -> 208 -> 13 col-tiles
#define SC_V  7      // GEMM2 K padded 224 -> 7 chunks of 32
#define NT2V  4      // out 49 -> 64 -> 4 tiles

#define HSTR 40      // LDS H-scratch row stride in halves (80 B: 16B-aligned)
#define WAVES 8

__device__ __forceinline__ float gelu_f(float x) {
  // exact gelu via A&S 7.1.26 erf approx, |err(erf)| < 1.5e-7
  float ax = fabsf(x) * 0.70710678118654752440f;
  float t  = 1.0f / (1.0f + 0.3275911f * ax);
  float p  = t * (0.254829592f + t * (-0.284496736f + t * (1.421413741f +
             t * (-1.453152027f + t * 1.061405429f))));
  float e  = __expf(-ax * ax);
  float erfv = 1.0f - p * e;
  float s  = (x >= 0.0f) ? erfv : -erfv;
  return 0.5f * x * (1.0f + s);
}

// Pack weights fp32->fp16 into MFMA fragment-major layout:
// frag[(s*NT + nt)*64 + lane][j] = W[k = s*32 + (lane>>4)*8 + j][n = nt*16 + (lane&15)]
// Also builds ipm = argsort(perm): ipm[perm[k]] = k.
__global__ void pack_kernel(const float* __restrict__ cW1, const float* __restrict__ cb1,
                            const float* __restrict__ cW2, const float* __restrict__ cb2,
                            const float* __restrict__ vW1, const float* __restrict__ vb1,
                            const float* __restrict__ vW2, const float* __restrict__ vb2,
                            const int* __restrict__ perm,
                            _Float16* __restrict__ w1c, _Float16* __restrict__ w2c,
                            _Float16* __restrict__ w1v, _Float16* __restrict__ w2v,
                            float* __restrict__ b1c, float* __restrict__ w96c,
                            float* __restrict__ b2c, float* __restrict__ b1v,
                            float* __restrict__ b2v, int* __restrict__ ipm)
{
  int id = blockIdx.x * 256 + threadIdx.x;
  const int S0 = 3 * NT1C * 64;      // 4992
  const int S1 = SC_C * NT2C * 64;   // 4992
  const int S2 = 2 * NT1V * 64;      // 1664
  const int S3 = SC_V * NT2V * 64;   // 1792
  if (id < S0) {
    int s = id / (NT1C * 64), rem = id % (NT1C * 64), nt = rem / 64, l = rem % 64;
    int q = l >> 4, n = nt * 16 + (l & 15);
    half8 v;
    #pragma unroll
    for (int j = 0; j < 8; ++j) {
      int k = s * 32 + q * 8 + j;
      float x = (n < 388) ? cW1[k * 388 + n] : 0.0f;
      v[j] = (_Float16)x;
    }
    *(half8*)(w1c + (size_t)id * 8) = v;
    return;
  }
  id -= S0;
  if (id < S1) {
    int s = id / (NT2C * 64), rem = id % (NT2C * 64), nt = rem / 64, l = rem % 64;
    int q = l >> 4, n = nt * 16 + (l & 15);
    half8 v;
    #pragma unroll
    for (int j = 0; j < 8; ++j) {
      int k = s * 32 + q * 8 + j;
      float x = (k < 388) ? cW2[k * 96 + n] : 0.0f;
      v[j] = (_Float16)x;
    }
    *(half8*)(w2c + (size_t)id * 8) = v;
    return;
  }
  id -= S1;
  if (id < S2) {
    int s = id / (NT1V * 64), rem = id % (NT1V * 64), nt = rem / 64, l = rem % 64;
    int q = l >> 4, n = nt * 16 + (l & 15);
    half8 v;
    #pragma unroll
    for (int j = 0; j < 8; ++j) {
      int k = s * 32 + q * 8 + j;                        // row 48 = prior row
      float x = (k < 49 && n < 196) ? vW1[k * 196 + n] : 0.0f;
      v[j] = (_Float16)x;
    }
    *(half8*)(w1v + (size_t)id * 8) = v;
    return;
  }
  id -= S2;
  if (id < S3) {
    int s = id / (NT2V * 64), rem = id % (NT2V * 64), nt = rem / 64, l = rem % 64;
    int q = l >> 4, n = nt * 16 + (l & 15);
    half8 v;
    #pragma unroll
    for (int j = 0; j < 8; ++j) {
      int k = s * 32 + q * 8 + j;
      float x = (k < 196 && n < 49) ? vW2[k * 49 + n] : 0.0f;
      v[j] = (_Float16)x;
    }
    *(half8*)(w2v + (size_t)id * 8) = v;
    return;
  }
  id -= S3;
  if (id < 416) { b1c[id]  = (id < 388) ? cb1[id] : 0.0f; return; }
  id -= 416;
  if (id < 416) { w96c[id] = (id < 388) ? cW1[96 * 388 + id] : 0.0f; return; }
  id -= 416;
  if (id < 96)  { b2c[id]  = cb2[id]; return; }
  id -= 96;
  if (id < 208) { b1v[id]  = (id < 196) ? vb1[id] : 0.0f; return; }
  id -= 208;
  if (id < 64)  { b2v[id]  = (id < 49) ? vb2[id] : 0.0f; return; }
  id -= 64;
  if (id < EDGE) { ipm[perm[id]] = id; return; }
}

// Fully fused decoder: one block per batch row, message state M resident in LDS
// (var-order edge rows of 16 halves). All T iterations run locally.
// 512 threads / 8 waves => __launch_bounds__(512,2) => 256-VGPR budget, no spill
// (R4's 1024-thread version hit the 128-VGPR cap and spilled 4.9 GB to scratch).
// Check phase: gather ALL A-frags via ipm first, barrier, then compute+scatter
// (fixes R4's cross-wave gather/scatter race). Var phase: contiguous, hazard-free
// by row ownership. 3 barriers/iter.
__global__ __launch_bounds__(512, 2) void fused_kernel(
    const int* __restrict__ synd, const float* __restrict__ prior,
    const int* __restrict__ ipm, float* __restrict__ outp,
    const _Float16* __restrict__ W1c, const _Float16* __restrict__ W2c,
    const float* __restrict__ b1c, const float* __restrict__ w96c,
    const float* __restrict__ b2c,
    const _Float16* __restrict__ W1v, const _Float16* __restrict__ W2v,
    const float* __restrict__ b1v, const float* __restrict__ b2v, int T)
{
  __shared__ _Float16 M[EDGE * 16];          // 96 KiB message state
  __shared__ _Float16 HL[WAVES][32 * HSTR];  // 20 KiB per-wave H scratch

  const int tid = threadIdx.x, w = tid >> 6, l = tid & 63;
  const int q = l >> 4, c = l & 15;
  const int b = blockIdx.x;

  // ---- init M: M[3v+j][0] = prior[v], rest 0 (var order); 2 vars/thread ----
  #pragma unroll
  for (int h = 0; h < 2; ++h) {
    const int v = tid + h * 512;
    float pv = prior[v];
    half8 z = {0,0,0,0,0,0,0,0};
    half8 z0 = z; z0[0] = (_Float16)pv;
    _Float16* dst = M + v * 48;
    *(half8*)(dst)      = z0;  *(half8*)(dst + 8)  = z;
    *(half8*)(dst + 16) = z0;  *(half8*)(dst + 24) = z;
    *(half8*)(dst + 32) = z0;  *(half8*)(dst + 40) = z;
  }

  // ---- per-lane loop-invariant constants ----
  float sg[2][2];
  int ip_e[2][2][6];                   // [check-pass][rg][edge]
  #pragma unroll
  for (int p = 0; p < 2; ++p)
    #pragma unroll
    for (int rg = 0; rg < 2; ++rg) {
      const int chk = w * 64 + p * 32 + rg * 16 + c;
      sg[p][rg] = 1.0f - 2.0f * (float)synd[b * NCHK + chk];
      #pragma unroll
      for (int j = 0; j < 6; ++j) ip_e[p][rg][j] = ipm[chk * 6 + j];
    }
  const int hi = (l >> 5) & 1;         // q>>1
  float pr[4][2];                      // [var-pass][rg]
  #pragma unroll
  for (int vt = 0; vt < 4; ++vt)
    #pragma unroll
    for (int rg = 0; rg < 2; ++rg)
      pr[vt][rg] = prior[w * 128 + vt * 32 + rg * 16 + c];

  const half8* W1fc = (const half8*)W1c;
  const half8* W2fc = (const half8*)W2c;
  const half8* W1fv = (const half8*)W1v;
  const half8* W2fv = (const half8*)W2v;
  _Float16* Hb = &HL[w][0];

  __syncthreads();

  for (int t = 0; t < T; ++t) {
    // ================= CHECK PHASE (512 rows, 64/wave in 2 passes) ==========
    // Gather ALL inputs into registers first, then barrier, then compute+scatter.
    half8 mb[2][2][3];
    #pragma unroll
    for (int p = 0; p < 2; ++p)
      #pragma unroll
      for (int rg = 0; rg < 2; ++rg)
        #pragma unroll
        for (int ks = 0; ks < 3; ++ks) {
          const int ip = hi ? ip_e[p][rg][2 * ks + 1] : ip_e[p][rg][2 * ks];
          mb[p][rg][ks] = *(const half8*)(M + ip * 16 + (q & 1) * 8);
        }

    __syncthreads();   // all gathers done before any scatter below

    #pragma unroll
    for (int p = 0; p < 2; ++p) {
      floatx4 acc2[2][6];
      #pragma unroll
      for (int nt = 0; nt < 6; ++nt) {
        floatx4 bia = *(const floatx4*)(b2c + nt * 16 + q * 4);
        acc2[0][nt] = bia;
        acc2[1][nt] = bia;
      }

      #pragma unroll 2
      for (int s = 0; s < SC_C; ++s) {
        #pragma unroll
        for (int u = 0; u < 2; ++u) {
          const int nt = s * 2 + u;
          half8 wa0 = W1fc[(0 * NT1C + nt) * 64 + l];
          half8 wa1 = W1fc[(1 * NT1C + nt) * 64 + l];
          half8 wa2 = W1fc[(2 * NT1C + nt) * 64 + l];
          floatx4 bia = *(const floatx4*)(b1c  + nt * 16 + q * 4);
          floatx4 wsg = *(const floatx4*)(w96c + nt * 16 + q * 4);
          #pragma unroll
          for (int rg = 0; rg < 2; ++rg) {
            floatx4 a;
            #pragma unroll
            for (int r = 0; r < 4; ++r) a[r] = bia[r] + sg[p][rg] * wsg[r];
            a = __builtin_amdgcn_mfma_f32_16x16x32_f16(wa0, mb[p][rg][0], a, 0, 0, 0);
            a = __builtin_amdgcn_mfma_f32_16x16x32_f16(wa1, mb[p][rg][1], a, 0, 0, 0);
            a = __builtin_amdgcn_mfma_f32_16x16x32_f16(wa2, mb[p][rg][2], a, 0, 0, 0);
            half4 hh;
            #pragma unroll
            for (int r = 0; r < 4; ++r)
              hh[r] = (_Float16)gelu_f(a[r]);
            *(half4*)(Hb + (rg * 16 + c) * HSTR + u * 16 + q * 4) = hh;
          }
        }
        half8 hf0 = *(const half8*)(Hb + (c)      * HSTR + q * 8);
        half8 hf1 = *(const half8*)(Hb + (16 + c) * HSTR + q * 8);
        #pragma unroll
        for (int nt = 0; nt < 6; ++nt) {
          half8 wb = W2fc[(s * NT2C + nt) * 64 + l];
          acc2[0][nt] = __builtin_amdgcn_mfma_f32_16x16x32_f16(wb, hf0, acc2[0][nt], 0, 0, 0);
          acc2[1][nt] = __builtin_amdgcn_mfma_f32_16x16x32_f16(wb, hf1, acc2[1][nt], 0, 0, 0);
        }
      }

      // scatter outputs back to M via ipm (LDS 8B granules)
      #pragma unroll
      for (int rg = 0; rg < 2; ++rg)
        #pragma unroll
        for (int nt = 0; nt < 6; ++nt) {
          half4 yy;
          #pragma unroll
          for (int r = 0; r < 4; ++r)
            yy[r] = (_Float16)(acc2[rg][nt][r] * sg[p][rg]);
          *(half4*)(M + ip_e[p][rg][nt] * 16 + q * 4) = yy;
        }
    }

    __syncthreads();

    // ============ VAR PHASE (1024 rows, 128/wave in 4 passes) ===============
    #pragma unroll
    for (int vt = 0; vt < 4; ++vt) {
      const int vbase = w * 128 + vt * 32;
      half8 vb[2][2];
      #pragma unroll
      for (int rg = 0; rg < 2; ++rg) {
        const int v = vbase + rg * 16 + c;
        const _Float16* Xr = M + v * 48;
        vb[rg][0] = *(const half8*)(Xr + q * 8);
        half8 m1 = {0,0,0,0,0,0,0,0};
        if (q < 2) m1 = *(const half8*)(Xr + 32 + q * 8);
        else if (q == 2) m1[0] = (_Float16)pr[vt][rg];
        vb[rg][1] = m1;
      }

      floatx4 accv[2][4];
      #pragma unroll
      for (int nt = 0; nt < 4; ++nt) {
        floatx4 bia = *(const floatx4*)(b2v + nt * 16 + q * 4);
        accv[0][nt] = bia;
        accv[1][nt] = bia;
      }

      #pragma unroll 2
      for (int s = 0; s < SC_V; ++s) {
        #pragma unroll
        for (int u = 0; u < 2; ++u) {
          const int nt = s * 2 + u;
          if (nt < NT1V) {
            half8 wa0 = W1fv[(0 * NT1V + nt) * 64 + l];
            half8 wa1 = W1fv[(1 * NT1V + nt) * 64 + l];
            floatx4 bia = *(const floatx4*)(b1v + nt * 16 + q * 4);
            #pragma unroll
            for (int rg = 0; rg < 2; ++rg) {
              floatx4 a = bia;
              a = __builtin_amdgcn_mfma_f32_16x16x32_f16(wa0, vb[rg][0], a, 0, 0, 0);
              a = __builtin_amdgcn_mfma_f32_16x16x32_f16(wa1, vb[rg][1], a, 0, 0, 0);
              half4 hh;
              #pragma unroll
              for (int r = 0; r < 4; ++r)
                hh[r] = (_Float16)gelu_f(a[r]);
              *(half4*)(Hb + (rg * 16 + c) * HSTR + u * 16 + q * 4) = hh;
            }
          } else {
            half4 hz = {0,0,0,0};
            #pragma unroll
            for (int rg = 0; rg < 2; ++rg)
              *(half4*)(Hb + (rg * 16 + c) * HSTR + u * 16 + q * 4) = hz;
          }
        }
        half8 hf0 = *(const half8*)(Hb + (c)      * HSTR + q * 8);
        half8 hf1 = *(const half8*)(Hb + (16 + c) * HSTR + q * 8);
        #pragma unroll
        for (int nt = 0; nt < 4; ++nt) {
          half8 wb = W2fv[(s * NT2V + nt) * 64 + l];
          accv[0][nt] = __builtin_amdgcn_mfma_f32_16x16x32_f16(wb, hf0, accv[0][nt], 0, 0, 0);
          accv[1][nt] = __builtin_amdgcn_mfma_f32_16x16x32_f16(wb, hf1, accv[1][nt], 0, 0, 0);
        }
      }

      // write back new messages (contiguous, var order) + llr to global
      #pragma unroll
      for (int rg = 0; rg < 2; ++rg) {
        const int v = vbase + rg * 16 + c;
        #pragma unroll
        for (int nt = 0; nt < 3; ++nt) {
          half4 yy;
          #pragma unroll
          for (int r = 0; r < 4; ++r)
            yy[r] = (_Float16)accv[rg][nt][r];
          *(half4*)(M + v * 48 + nt * 16 + q * 4) = yy;
        }
        if (q == 0)
          outp[(size_t)t * (BATCH * NVAR) + b * NVAR + v] = accv[rg][3][0];
      }
    }

    __syncthreads();
  }
}

extern "C" void kernel_launch(void* const* d_in, const int* in_sizes, int n_in,
                              void* d_out, int out_size, void* d_ws, size_t ws_size,
                              hipStream_t stream)
{
  const int*   synd  = (const int*)d_in[0];
  const float* prior = (const float*)d_in[2];
  const int*   perm  = (const int*)d_in[3];
  const float* cW1 = (const float*)d_in[4];
  const float* cb1 = (const float*)d_in[5];
  const float* cW2 = (const float*)d_in[6];
  const float* cb2 = (const float*)d_in[7];
  const float* vW1 = (const float*)d_in[8];
  const float* vb1 = (const float*)d_in[9];
  const float* vW2 = (const float*)d_in[10];
  const float* vb2 = (const float*)d_in[11];
  float* outp = (float*)d_out;
  const int T = out_size / (BATCH * NVAR);

  char* p = (char*)d_ws;
  _Float16* w1c = (_Float16*)p; p += (size_t)3 * NT1C * 64 * 8 * 2;
  _Float16* w2c = (_Float16*)p; p += (size_t)SC_C * NT2C * 64 * 8 * 2;
  _Float16* w1v = (_Float16*)p; p += (size_t)2 * NT1V * 64 * 8 * 2;
  _Float16* w2v = (_Float16*)p; p += (size_t)SC_V * NT2V * 64 * 8 * 2;
  float* b1c  = (float*)p; p += 416 * 4;
  float* w96c = (float*)p; p += 416 * 4;
  float* b2c  = (float*)p; p += 96 * 4;
  float* b1v  = (float*)p; p += 208 * 4;
  float* b2v  = (float*)p; p += 64 * 4;
  int*   ipm  = (int*)p;   p += EDGE * 4;

  pack_kernel<<<(17712 + 255) / 256, 256, 0, stream>>>(
      cW1, cb1, cW2, cb2, vW1, vb1, vW2, vb2, perm,
      w1c, w2c, w1v, w2v, b1c, w96c, b2c, b1v, b2v, ipm);

  fused_kernel<<<BATCH, 512, 0, stream>>>(
      synd, prior, ipm, outp,
      w1c, w2c, b1c, w96c, b2c, w1v, w2v, b1v, b2v, T);
}

// Round 6
// 1585.612 us; speedup vs baseline: 1.1999x; 1.1109x over previous
//
#include <hip/hip_runtime.h>
#include <cstdint>
#include <cstddef>

typedef _Float16 half8 __attribute__((ext_vector_type(8)));
typedef _Float16 half4 __attribute__((ext_vector_type(4)));
typedef float floatx4 __attribute__((ext_vector_type(4)));

#define BATCH 256
#define NCHK 512
#define NVAR 1024
#define EDGE 3072

// ---- check MLP tiling ----
#define NT1C  26     // hidden 388 -> 416 -> 26 col-tiles
#define SC_C  13     // 13 chunks of 32 hidden
#define NT2C  6      // out 96 -> 6 tiles
// ---- var MLP tiling ----
#define NT1V  13     // hidden 196 -> 208 -> 13 col-tiles
#define SC_V  7      // GEMM2 K padded 224 -> 7 chunks of 32
#define NT2V  4      // out 49 -> 64 -> 4 tiles

#define HSTR 40      // LDS H-scratch row stride in halves (80 B: 16B-aligned)
#define WAVES 8

__device__ __forceinline__ float gelu_f(float x) {
  // exact gelu via A&S 7.1.26 erf approx, |err(erf)| < 1.5e-7
  float ax = fabsf(x) * 0.70710678118654752440f;
  float t  = 1.0f / (1.0f + 0.3275911f * ax);
  float p  = t * (0.254829592f + t * (-0.284496736f + t * (1.421413741f +
             t * (-1.453152027f + t * 1.061405429f))));
  float e  = __expf(-ax * ax);
  float erfv = 1.0f - p * e;
  float s  = (x >= 0.0f) ? erfv : -erfv;
  return 0.5f * x * (1.0f + s);
}

// Pack weights fp32->fp16 into MFMA fragment-major layout:
// frag[(s*NT + nt)*64 + lane][j] = W[k = s*32 + (lane>>4)*8 + j][n = nt*16 + (lane&15)]
// Also builds ipm = argsort(perm): ipm[perm[k]] = k.
__global__ void pack_kernel(const float* __restrict__ cW1, const float* __restrict__ cb1,
                            const float* __restrict__ cW2, const float* __restrict__ cb2,
                            const float* __restrict__ vW1, const float* __restrict__ vb1,
                            const float* __restrict__ vW2, const float* __restrict__ vb2,
                            const int* __restrict__ perm,
                            _Float16* __restrict__ w1c, _Float16* __restrict__ w2c,
                            _Float16* __restrict__ w1v, _Float16* __restrict__ w2v,
                            float* __restrict__ b1c, float* __restrict__ w96c,
                            float* __restrict__ b2c, float* __restrict__ b1v,
                            float* __restrict__ b2v, int* __restrict__ ipm)
{
  int id = blockIdx.x * 256 + threadIdx.x;
  const int S0 = 3 * NT1C * 64;      // 4992
  const int S1 = SC_C * NT2C * 64;   // 4992
  const int S2 = 2 * NT1V * 64;      // 1664
  const int S3 = SC_V * NT2V * 64;   // 1792
  if (id < S0) {
    int s = id / (NT1C * 64), rem = id % (NT1C * 64), nt = rem / 64, l = rem % 64;
    int q = l >> 4, n = nt * 16 + (l & 15);
    half8 v;
    #pragma unroll
    for (int j = 0; j < 8; ++j) {
      int k = s * 32 + q * 8 + j;
      float x = (n < 388) ? cW1[k * 388 + n] : 0.0f;
      v[j] = (_Float16)x;
    }
    *(half8*)(w1c + (size_t)id * 8) = v;
    return;
  }
  id -= S0;
  if (id < S1) {
    int s = id / (NT2C * 64), rem = id % (NT2C * 64), nt = rem / 64, l = rem % 64;
    int q = l >> 4, n = nt * 16 + (l & 15);
    half8 v;
    #pragma unroll
    for (int j = 0; j < 8; ++j) {
      int k = s * 32 + q * 8 + j;
      float x = (k < 388) ? cW2[k * 96 + n] : 0.0f;
      v[j] = (_Float16)x;
    }
    *(half8*)(w2c + (size_t)id * 8) = v;
    return;
  }
  id -= S1;
  if (id < S2) {
    int s = id / (NT1V * 64), rem = id % (NT1V * 64), nt = rem / 64, l = rem % 64;
    int q = l >> 4, n = nt * 16 + (l & 15);
    half8 v;
    #pragma unroll
    for (int j = 0; j < 8; ++j) {
      int k = s * 32 + q * 8 + j;                        // row 48 = prior row
      float x = (k < 49 && n < 196) ? vW1[k * 196 + n] : 0.0f;
      v[j] = (_Float16)x;
    }
    *(half8*)(w1v + (size_t)id * 8) = v;
    return;
  }
  id -= S2;
  if (id < S3) {
    int s = id / (NT2V * 64), rem = id % (NT2V * 64), nt = rem / 64, l = rem % 64;
    int q = l >> 4, n = nt * 16 + (l & 15);
    half8 v;
    #pragma unroll
    for (int j = 0; j < 8; ++j) {
      int k = s * 32 + q * 8 + j;
      float x = (k < 196 && n < 49) ? vW2[k * 49 + n] : 0.0f;
      v[j] = (_Float16)x;
    }
    *(half8*)(w2v + (size_t)id * 8) = v;
    return;
  }
  id -= S3;
  if (id < 416) { b1c[id]  = (id < 388) ? cb1[id] : 0.0f; return; }
  id -= 416;
  if (id < 416) { w96c[id] = (id < 388) ? cW1[96 * 388 + id] : 0.0f; return; }
  id -= 416;
  if (id < 96)  { b2c[id]  = cb2[id]; return; }
  id -= 96;
  if (id < 208) { b1v[id]  = (id < 196) ? vb1[id] : 0.0f; return; }
  id -= 208;
  if (id < 64)  { b2v[id]  = (id < 49) ? vb2[id] : 0.0f; return; }
  id -= 64;
  if (id < EDGE) { ipm[perm[id]] = id; return; }
}

// Fully fused decoder: one block per batch row, message state M resident in LDS
// (var-order edge rows of 16 halves). All T iterations run locally.
//
// __launch_bounds__(512, 1): measured evidence (R4: (1024,4)->64 VGPR,
// R5: (512,2)->128 VGPR) shows arg2 acts as min BLOCKS/CU (CUDA semantics),
// so ask for 1 block -> 8 waves/CU -> 256-VGPR budget -> no scratch spill.
//
// Ownership: check chk reads AND writes exactly edges ipm[chk*6..+6] (same
// wave, in-order DS ops); var v reads/writes rows 3v..3v+2. No intra-phase
// cross-wave hazards => only 2 barriers per iteration (between phases).
__global__ __launch_bounds__(512, 1) void fused_kernel(
    const int* __restrict__ synd, const float* __restrict__ prior,
    const int* __restrict__ ipm, float* __restrict__ outp,
    const _Float16* __restrict__ W1c, const _Float16* __restrict__ W2c,
    const float* __restrict__ b1c, const float* __restrict__ w96c,
    const float* __restrict__ b2c,
    const _Float16* __restrict__ W1v, const _Float16* __restrict__ W2v,
    const float* __restrict__ b1v, const float* __restrict__ b2v, int T)
{
  __shared__ _Float16 M[EDGE * 16];          // 96 KiB message state
  __shared__ _Float16 HL[WAVES][32 * HSTR];  // 20 KiB per-wave H scratch

  const int tid = threadIdx.x, w = tid >> 6, l = tid & 63;
  const int q = l >> 4, c = l & 15;
  const int b = blockIdx.x;
  const int hi = (l >> 5) & 1;         // q>>1

  // ---- init M: M[3v+j][0] = prior[v], rest 0 (var order); 2 vars/thread ----
  #pragma unroll
  for (int h = 0; h < 2; ++h) {
    const int v = tid + h * 512;
    float pv = prior[v];
    half8 z = {0,0,0,0,0,0,0,0};
    half8 z0 = z; z0[0] = (_Float16)pv;
    _Float16* dst = M + v * 48;
    *(half8*)(dst)      = z0;  *(half8*)(dst + 8)  = z;
    *(half8*)(dst + 16) = z0;  *(half8*)(dst + 24) = z;
    *(half8*)(dst + 32) = z0;  *(half8*)(dst + 40) = z;
  }

  const half8* W1fc = (const half8*)W1c;
  const half8* W2fc = (const half8*)W2c;
  const half8* W1fv = (const half8*)W1v;
  const half8* W2fv = (const half8*)W2v;
  _Float16* Hb = &HL[w][0];

  __syncthreads();

  for (int t = 0; t < T; ++t) {
    // ============ CHECK PHASE (512 rows, 64/wave in 2 sequential passes) =====
    #pragma unroll 1
    for (int p = 0; p < 2; ++p) {
      // per-pass constants (L1-hit reloads; keeps register pressure low)
      int ipv[2][6];
      float sg[2];
      #pragma unroll
      for (int rg = 0; rg < 2; ++rg) {
        const int chk = w * 64 + p * 32 + rg * 16 + c;
        sg[rg] = 1.0f - 2.0f * (float)synd[b * NCHK + chk];
        #pragma unroll
        for (int j = 0; j < 6; ++j) ipv[rg][j] = ipm[chk * 6 + j];
      }

      // gather this pass's A-fragments from M (own edges; same-wave ordering)
      half8 mb[2][3];
      #pragma unroll
      for (int rg = 0; rg < 2; ++rg)
        #pragma unroll
        for (int ks = 0; ks < 3; ++ks)
          mb[rg][ks] = *(const half8*)(M + ipv[rg][2 * ks + hi] * 16 + (q & 1) * 8);

      floatx4 acc2[2][6];
      #pragma unroll
      for (int nt = 0; nt < 6; ++nt) {
        floatx4 bia = *(const floatx4*)(b2c + nt * 16 + q * 4);
        acc2[0][nt] = bia;
        acc2[1][nt] = bia;
      }

      #pragma unroll 2
      for (int s = 0; s < SC_C; ++s) {
        #pragma unroll
        for (int u = 0; u < 2; ++u) {
          const int nt = s * 2 + u;
          half8 wa0 = W1fc[(0 * NT1C + nt) * 64 + l];
          half8 wa1 = W1fc[(1 * NT1C + nt) * 64 + l];
          half8 wa2 = W1fc[(2 * NT1C + nt) * 64 + l];
          floatx4 bia = *(const floatx4*)(b1c  + nt * 16 + q * 4);
          floatx4 wsg = *(const floatx4*)(w96c + nt * 16 + q * 4);
          #pragma unroll
          for (int rg = 0; rg < 2; ++rg) {
            floatx4 a;
            #pragma unroll
            for (int r = 0; r < 4; ++r) a[r] = bia[r] + sg[rg] * wsg[r];
            a = __builtin_amdgcn_mfma_f32_16x16x32_f16(wa0, mb[rg][0], a, 0, 0, 0);
            a = __builtin_amdgcn_mfma_f32_16x16x32_f16(wa1, mb[rg][1], a, 0, 0, 0);
            a = __builtin_amdgcn_mfma_f32_16x16x32_f16(wa2, mb[rg][2], a, 0, 0, 0);
            half4 hh;
            #pragma unroll
            for (int r = 0; r < 4; ++r)
              hh[r] = (_Float16)gelu_f(a[r]);
            *(half4*)(Hb + (rg * 16 + c) * HSTR + u * 16 + q * 4) = hh;
          }
        }
        half8 hf0 = *(const half8*)(Hb + (c)      * HSTR + q * 8);
        half8 hf1 = *(const half8*)(Hb + (16 + c) * HSTR + q * 8);
        #pragma unroll
        for (int nt = 0; nt < 6; ++nt) {
          half8 wb = W2fc[(s * NT2C + nt) * 64 + l];
          acc2[0][nt] = __builtin_amdgcn_mfma_f32_16x16x32_f16(wb, hf0, acc2[0][nt], 0, 0, 0);
          acc2[1][nt] = __builtin_amdgcn_mfma_f32_16x16x32_f16(wb, hf1, acc2[1][nt], 0, 0, 0);
        }
      }

      // scatter outputs back to M via ipv (LDS 8B granules, own edges)
      #pragma unroll
      for (int rg = 0; rg < 2; ++rg)
        #pragma unroll
        for (int nt = 0; nt < 6; ++nt) {
          half4 yy;
          #pragma unroll
          for (int r = 0; r < 4; ++r)
            yy[r] = (_Float16)(acc2[rg][nt][r] * sg[rg]);
          *(half4*)(M + ipv[rg][nt] * 16 + q * 4) = yy;
        }
    }

    __syncthreads();

    // ============ VAR PHASE (1024 rows, 128/wave in 4 sequential passes) =====
    #pragma unroll 1
    for (int vt = 0; vt < 4; ++vt) {
      const int vbase = w * 128 + vt * 32;
      half8 vb[2][2];
      #pragma unroll
      for (int rg = 0; rg < 2; ++rg) {
        const int v = vbase + rg * 16 + c;
        const _Float16* Xr = M + v * 48;
        vb[rg][0] = *(const half8*)(Xr + q * 8);
        half8 m1 = {0,0,0,0,0,0,0,0};
        if (q < 2) m1 = *(const half8*)(Xr + 32 + q * 8);
        else if (q == 2) m1[0] = (_Float16)prior[v];
        vb[rg][1] = m1;
      }

      floatx4 accv[2][4];
      #pragma unroll
      for (int nt = 0; nt < 4; ++nt) {
        floatx4 bia = *(const floatx4*)(b2v + nt * 16 + q * 4);
        accv[0][nt] = bia;
        accv[1][nt] = bia;
      }

      #pragma unroll 2
      for (int s = 0; s < SC_V; ++s) {
        #pragma unroll
        for (int u = 0; u < 2; ++u) {
          const int nt = s * 2 + u;
          if (nt < NT1V) {
            half8 wa0 = W1fv[(0 * NT1V + nt) * 64 + l];
            half8 wa1 = W1fv[(1 * NT1V + nt) * 64 + l];
            floatx4 bia = *(const floatx4*)(b1v + nt * 16 + q * 4);
            #pragma unroll
            for (int rg = 0; rg < 2; ++rg) {
              floatx4 a = bia;
              a = __builtin_amdgcn_mfma_f32_16x16x32_f16(wa0, vb[rg][0], a, 0, 0, 0);
              a = __builtin_amdgcn_mfma_f32_16x16x32_f16(wa1, vb[rg][1], a, 0, 0, 0);
              half4 hh;
              #pragma unroll
              for (int r = 0; r < 4; ++r)
                hh[r] = (_Float16)gelu_f(a[r]);
              *(half4*)(Hb + (rg * 16 + c) * HSTR + u * 16 + q * 4) = hh;
            }
          } else {
            half4 hz = {0,0,0,0};
            #pragma unroll
            for (int rg = 0; rg < 2; ++rg)
              *(half4*)(Hb + (rg * 16 + c) * HSTR + u * 16 + q * 4) = hz;
          }
        }
        half8 hf0 = *(const half8*)(Hb + (c)      * HSTR + q * 8);
        half8 hf1 = *(const half8*)(Hb + (16 + c) * HSTR + q * 8);
        #pragma unroll
        for (int nt = 0; nt < 4; ++nt) {
          half8 wb = W2fv[(s * NT2V + nt) * 64 + l];
          accv[0][nt] = __builtin_amdgcn_mfma_f32_16x16x32_f16(wb, hf0, accv[0][nt], 0, 0, 0);
          accv[1][nt] = __builtin_amdgcn_mfma_f32_16x16x32_f16(wb, hf1, accv[1][nt], 0, 0, 0);
        }
      }

      // write back new messages (contiguous, var order) + llr to global
      #pragma unroll
      for (int rg = 0; rg < 2; ++rg) {
        const int v = vbase + rg * 16 + c;
        #pragma unroll
        for (int nt = 0; nt < 3; ++nt) {
          half4 yy;
          #pragma unroll
          for (int r = 0; r < 4; ++r)
            yy[r] = (_Float16)accv[rg][nt][r];
          *(half4*)(M + v * 48 + nt * 16 + q * 4) = yy;
        }
        if (q == 0)
          outp[(size_t)t * (BATCH * NVAR) + b * NVAR + v] = accv[rg][3][0];
      }
    }

    __syncthreads();
  }
}

extern "C" void kernel_launch(void* const* d_in, const int* in_sizes, int n_in,
                              void* d_out, int out_size, void* d_ws, size_t ws_size,
                              hipStream_t stream)
{
  const int*   synd  = (const int*)d_in[0];
  const float* prior = (const float*)d_in[2];
  const int*   perm  = (const int*)d_in[3];
  const float* cW1 = (const float*)d_in[4];
  const float* cb1 = (const float*)d_in[5];
  const float* cW2 = (const float*)d_in[6];
  const float* cb2 = (const float*)d_in[7];
  const float* vW1 = (const float*)d_in[8];
  const float* vb1 = (const float*)d_in[9];
  const float* vW2 = (const float*)d_in[10];
  const float* vb2 = (const float*)d_in[11];
  float* outp = (float*)d_out;
  const int T = out_size / (BATCH * NVAR);

  char* p = (char*)d_ws;
  _Float16* w1c = (_Float16*)p; p += (size_t)3 * NT1C * 64 * 8 * 2;
  _Float16* w2c = (_Float16*)p; p += (size_t)SC_C * NT2C * 64 * 8 * 2;
  _Float16* w1v = (_Float16*)p; p += (size_t)2 * NT1V * 64 * 8 * 2;
  _Float16* w2v = (_Float16*)p; p += (size_t)SC_V * NT2V * 64 * 8 * 2;
  float* b1c  = (float*)p; p += 416 * 4;
  float* w96c = (float*)p; p += 416 * 4;
  float* b2c  = (float*)p; p += 96 * 4;
  float* b1v  = (float*)p; p += 208 * 4;
  float* b2v  = (float*)p; p += 64 * 4;
  int*   ipm  = (int*)p;   p += EDGE * 4;

  pack_kernel<<<(17712 + 255) / 256, 256, 0, stream>>>(
      cW1, cb1, cW2, cb2, vW1, vb1, vW2, vb2, perm,
      w1c, w2c, w1v, w2v, b1c, w96c, b2c, b1v, b2v, ipm);

  fused_kernel<<<BATCH, 512, 0, stream>>>(
      synd, prior, ipm, outp,
      w1c, w2c, b1c, w96c, b2c, w1v, w2v, b1v, b2v, T);
}

// Round 7
// 737.459 us; speedup vs baseline: 2.5799x; 2.1501x over previous
//
#include <hip/hip_runtime.h>
#include <cstdint>
#include <cstddef>

typedef _Float16 half8 __attribute__((ext_vector_type(8)));
typedef _Float16 half4 __attribute__((ext_vector_type(4)));
typedef float floatx4 __attribute__((ext_vector_type(4)));

#define BATCH 256
#define NCHK 512
#define NVAR 1024
#define EDGE 3072

// ---- check MLP tiling ----
#define NT1C  26     // hidden 388 -> 416 -> 26 col-tiles
#define SC_C  13     // 13 chunks of 32 hidden
#define NT2C  6      // out 96 -> 6 tiles
// ---- var MLP tiling ----
#define NT1V  13     // hidden 196 -> 208 -> 13 col-tiles
#define SC_V  7      // GEMM2 K padded 224 -> 7 chunks of 32
#define NT2V  4      // out 49 -> 64 -> 4 tiles

#define HSTR 40      // LDS H-scratch row stride in halves (80 B: 16B-aligned)
#define WAVES 8

__device__ __forceinline__ float gelu_f(float x) {
  // exact gelu via A&S 7.1.26 erf approx, |err(erf)| < 1.5e-7
  float ax = fabsf(x) * 0.70710678118654752440f;
  float t  = 1.0f / (1.0f + 0.3275911f * ax);
  float p  = t * (0.254829592f + t * (-0.284496736f + t * (1.421413741f +
             t * (-1.453152027f + t * 1.061405429f))));
  float e  = __expf(-ax * ax);
  float erfv = 1.0f - p * e;
  float s  = (x >= 0.0f) ? erfv : -erfv;
  return 0.5f * x * (1.0f + s);
}

// Pack weights fp32->fp16 into MFMA fragment-major layout:
// frag[(s*NT + nt)*64 + lane][j] = W[k = s*32 + (lane>>4)*8 + j][n = nt*16 + (lane&15)]
// Also builds ipm = argsort(perm): ipm[perm[k]] = k.
__global__ void pack_kernel(const float* __restrict__ cW1, const float* __restrict__ cb1,
                            const float* __restrict__ cW2, const float* __restrict__ cb2,
                            const float* __restrict__ vW1, const float* __restrict__ vb1,
                            const float* __restrict__ vW2, const float* __restrict__ vb2,
                            const int* __restrict__ perm,
                            _Float16* __restrict__ w1c, _Float16* __restrict__ w2c,
                            _Float16* __restrict__ w1v, _Float16* __restrict__ w2v,
                            float* __restrict__ b1c, float* __restrict__ w96c,
                            float* __restrict__ b2c, float* __restrict__ b1v,
                            float* __restrict__ b2v, int* __restrict__ ipm)
{
  int id = blockIdx.x * 256 + threadIdx.x;
  const int S0 = 3 * NT1C * 64;      // 4992
  const int S1 = SC_C * NT2C * 64;   // 4992
  const int S2 = 2 * NT1V * 64;      // 1664
  const int S3 = SC_V * NT2V * 64;   // 1792
  if (id < S0) {
    int s = id / (NT1C * 64), rem = id % (NT1C * 64), nt = rem / 64, l = rem % 64;
    int q = l >> 4, n = nt * 16 + (l & 15);
    half8 v;
    #pragma unroll
    for (int j = 0; j < 8; ++j) {
      int k = s * 32 + q * 8 + j;
      float x = (n < 388) ? cW1[k * 388 + n] : 0.0f;
      v[j] = (_Float16)x;
    }
    *(half8*)(w1c + (size_t)id * 8) = v;
    return;
  }
  id -= S0;
  if (id < S1) {
    int s = id / (NT2C * 64), rem = id % (NT2C * 64), nt = rem / 64, l = rem % 64;
    int q = l >> 4, n = nt * 16 + (l & 15);
    half8 v;
    #pragma unroll
    for (int j = 0; j < 8; ++j) {
      int k = s * 32 + q * 8 + j;
      float x = (k < 388) ? cW2[k * 96 + n] : 0.0f;
      v[j] = (_Float16)x;
    }
    *(half8*)(w2c + (size_t)id * 8) = v;
    return;
  }
  id -= S1;
  if (id < S2) {
    int s = id / (NT1V * 64), rem = id % (NT1V * 64), nt = rem / 64, l = rem % 64;
    int q = l >> 4, n = nt * 16 + (l & 15);
    half8 v;
    #pragma unroll
    for (int j = 0; j < 8; ++j) {
      int k = s * 32 + q * 8 + j;                        // row 48 = prior row
      float x = (k < 49 && n < 196) ? vW1[k * 196 + n] : 0.0f;
      v[j] = (_Float16)x;
    }
    *(half8*)(w1v + (size_t)id * 8) = v;
    return;
  }
  id -= S2;
  if (id < S3) {
    int s = id / (NT2V * 64), rem = id % (NT2V * 64), nt = rem / 64, l = rem % 64;
    int q = l >> 4, n = nt * 16 + (l & 15);
    half8 v;
    #pragma unroll
    for (int j = 0; j < 8; ++j) {
      int k = s * 32 + q * 8 + j;
      float x = (k < 196 && n < 49) ? vW2[k * 49 + n] : 0.0f;
      v[j] = (_Float16)x;
    }
    *(half8*)(w2v + (size_t)id * 8) = v;
    return;
  }
  id -= S3;
  if (id < 416) { b1c[id]  = (id < 388) ? cb1[id] : 0.0f; return; }
  id -= 416;
  if (id < 416) { w96c[id] = (id < 388) ? cW1[96 * 388 + id] : 0.0f; return; }
  id -= 416;
  if (id < 96)  { b2c[id]  = cb2[id]; return; }
  id -= 96;
  if (id < 208) { b1v[id]  = (id < 196) ? vb1[id] : 0.0f; return; }
  id -= 208;
  if (id < 64)  { b2v[id]  = (id < 49) ? vb2[id] : 0.0f; return; }
  id -= 64;
  if (id < EDGE) { ipm[perm[id]] = id; return; }
}

// Fully fused decoder: one block per batch row, message state M resident in LDS
// (var-order edge rows of 16 halves). All T iterations run locally.
//
// R7: 16 rows/wave/pass (was 32). Per-pass live set ~70-80 VGPRs — fits the
// 128-reg budget the allocator actually gives us (R4-R6 evidence), so the
// acc-spill-every-s-chunk pattern (5 KB/thread/iter scratch, 3.2 GB FETCH)
// must disappear. s-loops are unroll-1 to stop cross-iteration load hoisting.
//
// Ownership: check chk reads AND writes exactly edges ipm[chk*6..+6] (same
// wave, in-order DS ops); var v reads/writes rows 3v..3v+2. No intra-phase
// hazards => 2 barriers per iteration.
__global__ __launch_bounds__(512, 1) void fused_kernel(
    const int* __restrict__ synd, const float* __restrict__ prior,
    const int* __restrict__ ipm, float* __restrict__ outp,
    const _Float16* __restrict__ W1c, const _Float16* __restrict__ W2c,
    const float* __restrict__ b1c, const float* __restrict__ w96c,
    const float* __restrict__ b2c,
    const _Float16* __restrict__ W1v, const _Float16* __restrict__ W2v,
    const float* __restrict__ b1v, const float* __restrict__ b2v, int T)
{
  __shared__ _Float16 M[EDGE * 16];          // 96 KiB message state
  __shared__ _Float16 HL[WAVES][16 * HSTR];  // 10 KiB per-wave H scratch (16 rows)

  const int tid = threadIdx.x, w = tid >> 6, l = tid & 63;
  const int q = l >> 4, c = l & 15;
  const int b = blockIdx.x;
  const int hi = (l >> 5) & 1;         // q>>1

  // ---- init M: M[3v+j][0] = prior[v], rest 0 (var order); 2 vars/thread ----
  #pragma unroll
  for (int h = 0; h < 2; ++h) {
    const int v = tid + h * 512;
    float pv = prior[v];
    half8 z = {0,0,0,0,0,0,0,0};
    half8 z0 = z; z0[0] = (_Float16)pv;
    _Float16* dst = M + v * 48;
    *(half8*)(dst)      = z0;  *(half8*)(dst + 8)  = z;
    *(half8*)(dst + 16) = z0;  *(half8*)(dst + 24) = z;
    *(half8*)(dst + 32) = z0;  *(half8*)(dst + 40) = z;
  }

  const half8* W1fc = (const half8*)W1c;
  const half8* W2fc = (const half8*)W2c;
  const half8* W1fv = (const half8*)W1v;
  const half8* W2fv = (const half8*)W2v;
  _Float16* Hb = &HL[w][0];

  __syncthreads();

  for (int t = 0; t < T; ++t) {
    // ============ CHECK PHASE (512 rows; 16/wave/pass, 4 passes) ============
    #pragma unroll 1
    for (int p = 0; p < 4; ++p) {
      const int chk = p * 128 + w * 16 + c;
      const float sg = 1.0f - 2.0f * (float)synd[b * NCHK + chk];
      int ip[6];
      #pragma unroll
      for (int j = 0; j < 6; ++j) ip[j] = ipm[chk * 6 + j];

      // gather A-fragments (own edges; constant-indexed selects, no scratch)
      half8 mb[3];
      #pragma unroll
      for (int ks = 0; ks < 3; ++ks) {
        const int e = hi ? ip[2 * ks + 1] : ip[2 * ks];
        mb[ks] = *(const half8*)(M + e * 16 + (q & 1) * 8);
      }

      floatx4 acc[6];
      #pragma unroll
      for (int nt = 0; nt < 6; ++nt)
        acc[nt] = *(const floatx4*)(b2c + nt * 16 + q * 4);

      #pragma unroll 1
      for (int s = 0; s < SC_C; ++s) {
        #pragma unroll
        for (int u = 0; u < 2; ++u) {
          const int nt = s * 2 + u;
          half8 wa0 = W1fc[(0 * NT1C + nt) * 64 + l];
          half8 wa1 = W1fc[(1 * NT1C + nt) * 64 + l];
          half8 wa2 = W1fc[(2 * NT1C + nt) * 64 + l];
          floatx4 bia = *(const floatx4*)(b1c  + nt * 16 + q * 4);
          floatx4 wsg = *(const floatx4*)(w96c + nt * 16 + q * 4);
          floatx4 a;
          #pragma unroll
          for (int r = 0; r < 4; ++r) a[r] = bia[r] + sg * wsg[r];
          a = __builtin_amdgcn_mfma_f32_16x16x32_f16(wa0, mb[0], a, 0, 0, 0);
          a = __builtin_amdgcn_mfma_f32_16x16x32_f16(wa1, mb[1], a, 0, 0, 0);
          a = __builtin_amdgcn_mfma_f32_16x16x32_f16(wa2, mb[2], a, 0, 0, 0);
          half4 hh;
          #pragma unroll
          for (int r = 0; r < 4; ++r)
            hh[r] = (_Float16)gelu_f(a[r]);
          *(half4*)(Hb + c * HSTR + u * 16 + q * 4) = hh;
        }
        half8 hf = *(const half8*)(Hb + c * HSTR + q * 8);
        #pragma unroll
        for (int nt = 0; nt < 6; ++nt) {
          half8 wb = W2fc[(s * NT2C + nt) * 64 + l];
          acc[nt] = __builtin_amdgcn_mfma_f32_16x16x32_f16(wb, hf, acc[nt], 0, 0, 0);
        }
      }

      // scatter outputs back to M (own edges, LDS 8B granules)
      #pragma unroll
      for (int nt = 0; nt < 6; ++nt) {
        half4 yy;
        #pragma unroll
        for (int r = 0; r < 4; ++r)
          yy[r] = (_Float16)(acc[nt][r] * sg);
        *(half4*)(M + ip[nt] * 16 + q * 4) = yy;
      }
    }

    __syncthreads();

    // ============ VAR PHASE (1024 rows; 16/wave/pass, 8 passes) =============
    #pragma unroll 1
    for (int p = 0; p < 8; ++p) {
      const int v = p * 128 + w * 16 + c;
      const _Float16* Xr = M + v * 48;
      half8 vb0 = *(const half8*)(Xr + q * 8);
      half8 vb1 = {0,0,0,0,0,0,0,0};
      if (q < 2) vb1 = *(const half8*)(Xr + 32 + q * 8);
      else if (q == 2) vb1[0] = (_Float16)prior[v];

      floatx4 accv[4];
      #pragma unroll
      for (int nt = 0; nt < 4; ++nt)
        accv[nt] = *(const floatx4*)(b2v + nt * 16 + q * 4);

      #pragma unroll 1
      for (int s = 0; s < SC_V; ++s) {
        #pragma unroll
        for (int u = 0; u < 2; ++u) {
          const int nt = s * 2 + u;
          if (nt < NT1V) {
            half8 wa0 = W1fv[(0 * NT1V + nt) * 64 + l];
            half8 wa1 = W1fv[(1 * NT1V + nt) * 64 + l];
            floatx4 a = *(const floatx4*)(b1v + nt * 16 + q * 4);
            a = __builtin_amdgcn_mfma_f32_16x16x32_f16(wa0, vb0, a, 0, 0, 0);
            a = __builtin_amdgcn_mfma_f32_16x16x32_f16(wa1, vb1, a, 0, 0, 0);
            half4 hh;
            #pragma unroll
            for (int r = 0; r < 4; ++r)
              hh[r] = (_Float16)gelu_f(a[r]);
            *(half4*)(Hb + c * HSTR + u * 16 + q * 4) = hh;
          } else {
            half4 hz = {0,0,0,0};
            *(half4*)(Hb + c * HSTR + u * 16 + q * 4) = hz;
          }
        }
        half8 hf = *(const half8*)(Hb + c * HSTR + q * 8);
        #pragma unroll
        for (int nt = 0; nt < 4; ++nt) {
          half8 wb = W2fv[(s * NT2V + nt) * 64 + l];
          accv[nt] = __builtin_amdgcn_mfma_f32_16x16x32_f16(wb, hf, accv[nt], 0, 0, 0);
        }
      }

      // write back new messages (own rows, contiguous) + llr to global
      #pragma unroll
      for (int nt = 0; nt < 3; ++nt) {
        half4 yy;
        #pragma unroll
        for (int r = 0; r < 4; ++r)
          yy[r] = (_Float16)accv[nt][r];
        *(half4*)(M + v * 48 + nt * 16 + q * 4) = yy;
      }
      if (q == 0)
        outp[(size_t)t * (BATCH * NVAR) + b * NVAR + v] = accv[3][0];
    }

    __syncthreads();
  }
}

extern "C" void kernel_launch(void* const* d_in, const int* in_sizes, int n_in,
                              void* d_out, int out_size, void* d_ws, size_t ws_size,
                              hipStream_t stream)
{
  const int*   synd  = (const int*)d_in[0];
  const float* prior = (const float*)d_in[2];
  const int*   perm  = (const int*)d_in[3];
  const float* cW1 = (const float*)d_in[4];
  const float* cb1 = (const float*)d_in[5];
  const float* cW2 = (const float*)d_in[6];
  const float* cb2 = (const float*)d_in[7];
  const float* vW1 = (const float*)d_in[8];
  const float* vb1 = (const float*)d_in[9];
  const float* vW2 = (const float*)d_in[10];
  const float* vb2 = (const float*)d_in[11];
  float* outp = (float*)d_out;
  const int T = out_size / (BATCH * NVAR);

  char* p = (char*)d_ws;
  _Float16* w1c = (_Float16*)p; p += (size_t)3 * NT1C * 64 * 8 * 2;
  _Float16* w2c = (_Float16*)p; p += (size_t)SC_C * NT2C * 64 * 8 * 2;
  _Float16* w1v = (_Float16*)p; p += (size_t)2 * NT1V * 64 * 8 * 2;
  _Float16* w2v = (_Float16*)p; p += (size_t)SC_V * NT2V * 64 * 8 * 2;
  float* b1c  = (float*)p; p += 416 * 4;
  float* w96c = (float*)p; p += 416 * 4;
  float* b2c  = (float*)p; p += 96 * 4;
  float* b1v  = (float*)p; p += 208 * 4;
  float* b2v  = (float*)p; p += 64 * 4;
  int*   ipm  = (int*)p;   p += EDGE * 4;

  pack_kernel<<<(17712 + 255) / 256, 256, 0, stream>>>(
      cW1, cb1, cW2, cb2, vW1, vb1, vW2, vb2, perm,
      w1c, w2c, w1v, w2v, b1c, w96c, b2c, b1v, b2v, ipm);

  fused_kernel<<<BATCH, 512, 0, stream>>>(
      synd, prior, ipm, outp,
      w1c, w2c, b1c, w96c, b2c, w1v, w2v, b1v, b2v, T);
}